// Round 9
// baseline (284.616 us; speedup 1.0000x reference)
//
#include <hip/hip_runtime.h>

// ---------------------------------------------------------------------------
// GAT (3 layers) + attention pooling + regressor.
// GEMMs: split-bf16 MFMA (a_hi+a_lo, 3 products, f32 accum), A staged in LDS
// via global_load_lds; attn scores fused into GEMM epilogue; h stored
// HEAD-MAJOR [H][N][64] so the aggregate gathers from a 5.1MB/head set.
// Aggregates: one wave per (dst,head), batched weights, 8-deep prefetch.
// N=20000 nodes, E=320000 edges (+N self loops), H=4 heads, C=64, B=16 graphs.
// ---------------------------------------------------------------------------

typedef unsigned short u16;
typedef __attribute__((ext_vector_type(8))) short bf16x8;
typedef __attribute__((ext_vector_type(4))) float f32x4;

__device__ __forceinline__ u16 bf16rn(float x) {
    unsigned u = __float_as_uint(x);
    u += 0x7FFFu + ((u >> 16) & 1u);
    return (u16)(u >> 16);
}
__device__ __forceinline__ float bf16f(u16 h) {
    return __uint_as_float(((unsigned)h) << 16);
}

__device__ __forceinline__ void gload16(const u16* g, u16* l) {
    __builtin_amdgcn_global_load_lds(
        (const __attribute__((address_space(1))) unsigned int*)g,
        (__attribute__((address_space(3))) unsigned int*)l, 16, 0, 0);
}

// ---------------- CSR-by-destination build ----------------
__global__ void edge_hist_k(const int* __restrict__ ei, int E, int n, int* __restrict__ deg) {
    int i = blockIdx.x * blockDim.x + threadIdx.x;
    if (i >= E + n) return;
    int dst = (i < E) ? ei[E + i] : (i - E);   // self-loop for i >= E
    atomicAdd(&deg[dst], 1);
}

__global__ __launch_bounds__(1024) void scan_excl_k(const int* __restrict__ deg, int* __restrict__ rowptr,
                                                    int* __restrict__ cursor, int n) {
    __shared__ int part[1024];
    int tid = threadIdx.x;
    int chunk = (n + 1023) / 1024;
    int lo = tid * chunk;
    int hi = lo + chunk;
    if (lo > n) lo = n;
    if (hi > n) hi = n;
    int s = 0;
    for (int i = lo; i < hi; ++i) s += deg[i];
    part[tid] = s;
    __syncthreads();
    for (int off = 1; off < 1024; off <<= 1) {
        int v = (tid >= off) ? part[tid - off] : 0;
        __syncthreads();
        part[tid] += v;
        __syncthreads();
    }
    int run = (tid == 0) ? 0 : part[tid - 1];
    for (int i = lo; i < hi; ++i) {
        rowptr[i] = run;
        cursor[i] = run;
        run += deg[i];
    }
    if (tid == 1023) rowptr[n] = run;
}

__global__ void edge_scatter_k(const int* __restrict__ ei, int E, int n,
                               int* __restrict__ cursor, int* __restrict__ srcs) {
    int i = blockIdx.x * blockDim.x + threadIdx.x;
    if (i >= E + n) return;
    int src, dst;
    if (i < E) { src = ei[i]; dst = ei[E + i]; }
    else       { src = i - E; dst = src; }
    int pos = atomicAdd(&cursor[dst], 1);
    srcs[pos] = src;
}

// ---------------- bf16 split conversions ----------------
__global__ void split_bf16_k(const float* __restrict__ in, u16* __restrict__ hi,
                             u16* __restrict__ lo, int n4) {
    int i = blockIdx.x * 256 + threadIdx.x;
    if (i >= n4) return;
    float4 v = reinterpret_cast<const float4*>(in)[i];
    u16 hx = bf16rn(v.x), hy = bf16rn(v.y), hz = bf16rn(v.z), hw = bf16rn(v.w);
    ushort4 H = make_ushort4(hx, hy, hz, hw);
    ushort4 L = make_ushort4(bf16rn(v.x - bf16f(hx)), bf16rn(v.y - bf16f(hy)),
                             bf16rn(v.z - bf16f(hz)), bf16rn(v.w - bf16f(hw)));
    reinterpret_cast<ushort4*>(hi)[i] = H;
    reinterpret_cast<ushort4*>(lo)[i] = L;
}

// W[K][Nn] row-major -> transposed split Wt[Nn][K] (hi, lo)
__global__ void splitT_bf16_k(const float* __restrict__ W, u16* __restrict__ thi,
                              u16* __restrict__ tlo, int K, int Nn) {
    int idx = blockIdx.x * 256 + threadIdx.x;
    if (idx >= K * Nn) return;
    int k = idx / Nn, nn = idx - k * Nn;
    float v = W[idx];
    u16 h = bf16rn(v);
    u16 l = bf16rn(v - bf16f(h));
    thi[(size_t)nn * K + k] = h;
    tlo[(size_t)nn * K + k] = l;
}

// ---------------- split-bf16 MFMA GEMM, LDS-staged A, fused attn scores ----
// C emitted HEAD-MAJOR: C[((col>>6)*M + row)*64 + (col&63)].
// Epilogue also emits esrc/edst [M][Nn/64]: per-row dot with a_src/a_dst.
template <int NF>
__global__ __launch_bounds__(256) void gemm_lds_k(
        const u16* __restrict__ Ahi, const u16* __restrict__ Alo,
        const u16* __restrict__ Bthi, const u16* __restrict__ Btlo,
        float* __restrict__ C,
        const float* __restrict__ a_src, const float* __restrict__ a_dst,
        float* __restrict__ esrc, float* __restrict__ edst,
        int M, int Nn, int K) {
    __shared__ u16 Ah[2][4][64 * 8];   // [buf][kg][row*8]
    __shared__ u16 Al[2][4][64 * 8];
    const int mb = (M + 63) >> 6;
    const int mi = blockIdx.x % mb;
    const int ni = blockIdx.x / mb;
    const int m0 = mi * 64;
    const int n0 = ni * (NF * 64);
    const int tid = threadIdx.x;
    const int wv = tid >> 6;
    const int lane = tid & 63;
    const int rr = lane & 15;
    const int kg = lane >> 4;

    int srow = m0 + lane; if (srow > M - 1) srow = M - 1;
    const u16* sh = Ahi + (size_t)srow * K + wv * 8;
    const u16* sl = Alo + (size_t)srow * K + wv * 8;

    const u16* pbh[NF];
    const u16* pbl[NF];
#pragma unroll
    for (int nf = 0; nf < NF; ++nf) {
        int col = n0 + (wv * NF + nf) * 16 + rr;
        pbh[nf] = Bthi + (size_t)col * K + kg * 8;
        pbl[nf] = Btlo + (size_t)col * K + kg * 8;
    }

    f32x4 acc[4][NF];
#pragma unroll
    for (int mf = 0; mf < 4; ++mf)
#pragma unroll
        for (int nf = 0; nf < NF; ++nf) acc[mf][nf] = (f32x4){0.f, 0.f, 0.f, 0.f};

    bf16x8 bhc[NF], blc[NF], bhn[NF], bln[NF];
#pragma unroll
    for (int nf = 0; nf < NF; ++nf) {
        bhc[nf] = *reinterpret_cast<const bf16x8*>(pbh[nf]);
        blc[nf] = *reinterpret_cast<const bf16x8*>(pbl[nf]);
    }
    gload16(sh, &Ah[0][wv][0]);
    gload16(sl, &Al[0][wv][0]);
    __syncthreads();

    const int NT = K >> 5;
    for (int t = 0; t < NT; ++t) {
        const int cur = t & 1;
        if (t + 1 < NT) {
            const int kc = (t + 1) << 5;
#pragma unroll
            for (int nf = 0; nf < NF; ++nf) {
                bhn[nf] = *reinterpret_cast<const bf16x8*>(pbh[nf] + kc);
                bln[nf] = *reinterpret_cast<const bf16x8*>(pbl[nf] + kc);
            }
            gload16(sh + kc, &Ah[cur ^ 1][wv][0]);
            gload16(sl + kc, &Al[cur ^ 1][wv][0]);
        }
        bf16x8 ah[4], al[4];
#pragma unroll
        for (int mf = 0; mf < 4; ++mf) {
            ah[mf] = *reinterpret_cast<const bf16x8*>(&Ah[cur][kg][(mf * 16 + rr) * 8]);
            al[mf] = *reinterpret_cast<const bf16x8*>(&Al[cur][kg][(mf * 16 + rr) * 8]);
        }
#pragma unroll
        for (int mf = 0; mf < 4; ++mf)
#pragma unroll
            for (int nf = 0; nf < NF; ++nf) {
                acc[mf][nf] = __builtin_amdgcn_mfma_f32_16x16x32_bf16(ah[mf], bhc[nf], acc[mf][nf], 0, 0, 0);
                acc[mf][nf] = __builtin_amdgcn_mfma_f32_16x16x32_bf16(ah[mf], blc[nf], acc[mf][nf], 0, 0, 0);
                acc[mf][nf] = __builtin_amdgcn_mfma_f32_16x16x32_bf16(al[mf], bhc[nf], acc[mf][nf], 0, 0, 0);
            }
#pragma unroll
        for (int nf = 0; nf < NF; ++nf) { bhc[nf] = bhn[nf]; blc[nf] = bln[nf]; }
        __syncthreads();
    }

    // ---- C store (head-major) ----
#pragma unroll
    for (int mf = 0; mf < 4; ++mf)
#pragma unroll
        for (int nf = 0; nf < NF; ++nf) {
            int col = n0 + (wv * NF + nf) * 16 + rr;
            float* cb = C + ((size_t)(col >> 6) * M) * 64 + (col & 63);
#pragma unroll
            for (int rg = 0; rg < 4; ++rg) {
                int row = m0 + mf * 16 + kg * 4 + rg;
                if (row < M) cb[(size_t)row * 64] = acc[mf][nf][rg];
            }
        }

    // ---- fused attention scores: per-row dot with a_src / a_dst ----
    float asv[NF], adv[NF];
#pragma unroll
    for (int nf = 0; nf < NF; ++nf) {
        int col = n0 + (wv * NF + nf) * 16 + rr;
        asv[nf] = a_src[col];
        adv[nf] = a_dst[col];
    }
    float ps[4][4], pd[4][4];   // [mf][rg]
#pragma unroll
    for (int mf = 0; mf < 4; ++mf)
#pragma unroll
        for (int rg = 0; rg < 4; ++rg) {
            float s = 0.f, dvv = 0.f;
#pragma unroll
            for (int nf = 0; nf < NF; ++nf) {
                s = fmaf(acc[mf][nf][rg], asv[nf], s);
                dvv = fmaf(acc[mf][nf][rg], adv[nf], dvv);
            }
#pragma unroll
            for (int off = 1; off < 16; off <<= 1) {
                s += __shfl_xor(s, off);
                dvv += __shfl_xor(dvv, off);
            }
            ps[mf][rg] = s;
            pd[mf][rg] = dvv;
        }
    // cross-wave combine via LDS (reuse Ah; all reads of it completed)
    float* sm_src = (float*)&Ah[0][0][0];     // [4 waves][64 rows]
    float* sm_dst = sm_src + 256;
    if (rr == 0) {
#pragma unroll
        for (int mf = 0; mf < 4; ++mf)
#pragma unroll
            for (int rg = 0; rg < 4; ++rg) {
                int rl = mf * 16 + kg * 4 + rg;
                sm_src[wv * 64 + rl] = ps[mf][rg];
                sm_dst[wv * 64 + rl] = pd[mf][rg];
            }
    }
    __syncthreads();
    if (tid < 64) {
        int row = m0 + tid;
        if (row < M) {
            const int HTOT = Nn >> 6;
            constexpr int WPH = 4 / NF;        // waves per head
#pragma unroll
            for (int hl = 0; hl < NF; ++hl) {
                float es = 0.f, edv = 0.f;
#pragma unroll
                for (int w = 0; w < WPH; ++w) {
                    es += sm_src[(hl * WPH + w) * 64 + tid];
                    edv += sm_dst[(hl * WPH + w) * 64 + tid];
                }
                int hg = ni * NF + hl;
                esrc[(size_t)row * HTOT + hg] = es;
                edst[(size_t)row * HTOT + hg] = edv;
            }
        }
    }
}

// ---------------- GAT aggregation, head-split: one wave per (dst, head) ----
// hm is head-major [4][n][64]; per-head working set 5.1MB -> L2-cacheable.
// Batched weights (one exp per lane per 64-edge chunk) + 8-deep prefetch.
__global__ __launch_bounds__(256) void gat_aggregate_hm_k(
        const float* __restrict__ hm, const float* __restrict__ esrc,
        const float* __restrict__ edst, const int* __restrict__ rowptr,
        const int* __restrict__ srcs, const float* __restrict__ bias,
        u16* __restrict__ ghi, u16* __restrict__ glo, int n) {
    int d = blockIdx.x * 4 + (threadIdx.x >> 6);
    int lane = threadIdx.x & 63;
    int hh = blockIdx.y;                        // head
    if (d >= n) return;
    const float* hbase = hm + (size_t)hh * n * 64;
    float ed = edst[d * 4 + hh];
    int lo = rowptr[d], hi = rowptr[d + 1];
    float den = 0.f, acc = 0.f;
    for (int base = lo; base < hi; base += 64) {
        int cnt = min(64, hi - base);
        int idx = base + lane;
        int s = srcs[(idx < hi) ? idx : lo];
        float e = esrc[s * 4 + hh] + ed;
        e = (e >= 0.f) ? e : 0.2f * e;          // leaky_relu(0.2)
        float w = (lane < cnt) ? __expf(e) : 0.f;
        float ws = w;
#pragma unroll
        for (int off = 1; off < 64; off <<= 1) ws += __shfl_xor(ws, off);
        den += ws;
        auto loadrow = [&](int j) -> float {
            j = (j < cnt) ? j : (cnt - 1);
            int sp = __shfl(s, j);
            return hbase[(size_t)sp * 64 + lane];
        };
        float p0 = loadrow(0), p1 = loadrow(1), p2 = loadrow(2), p3 = loadrow(3);
        float p4 = loadrow(4), p5 = loadrow(5), p6 = loadrow(6), p7 = loadrow(7);
        for (int j = 0; j < cnt; j += 8) {
            float q0 = p0, q1 = p1, q2 = p2, q3 = p3;
            float q4 = p4, q5 = p5, q6 = p6, q7 = p7;
            p0 = loadrow(j + 8);  p1 = loadrow(j + 9);
            p2 = loadrow(j + 10); p3 = loadrow(j + 11);
            p4 = loadrow(j + 12); p5 = loadrow(j + 13);
            p6 = loadrow(j + 14); p7 = loadrow(j + 15);
            acc = fmaf(__shfl(w, j), q0, acc);
            acc = fmaf(__shfl(w, j + 1), q1, acc);
            acc = fmaf(__shfl(w, j + 2), q2, acc);
            acc = fmaf(__shfl(w, j + 3), q3, acc);
            acc = fmaf(__shfl(w, j + 4), q4, acc);
            acc = fmaf(__shfl(w, j + 5), q5, acc);
            acc = fmaf(__shfl(w, j + 6), q6, acc);
            acc = fmaf(__shfl(w, j + 7), q7, acc);
        }
    }
    int c = hh * 64 + lane;
    float o = acc / den + bias[c];
    o = (o > 0.f) ? o : expm1f(o);              // ELU
    u16 oh = bf16rn(o);
    ghi[(size_t)d * 256 + c] = oh;
    glo[(size_t)d * 256 + c] = bf16rn(o - bf16f(oh));
}

// ---------------- layer-3 aggregate (1 head) fused with node attn gate ------
__global__ __launch_bounds__(256) void gat_aggregate1_attn_k(
        const float* __restrict__ hin, const float* __restrict__ esrc,
        const float* __restrict__ edst, const int* __restrict__ rowptr,
        const int* __restrict__ srcs, const float* __restrict__ bias,
        const float* __restrict__ wp, const float* __restrict__ bp,
        float* __restrict__ gout, float* __restrict__ attn, int n) {
    int d = blockIdx.x * 4 + (threadIdx.x >> 6);
    int lane = threadIdx.x & 63;
    if (d >= n) return;
    float ed = edst[d];
    int lo = rowptr[d], hi = rowptr[d + 1];
    float den = 0.f, acc = 0.f;
    for (int base = lo; base < hi; base += 64) {
        int cnt = min(64, hi - base);
        int idx = base + lane;
        int s = srcs[(idx < hi) ? idx : lo];
        float e = esrc[s] + ed;
        e = (e >= 0.f) ? e : 0.2f * e;
        float w = (lane < cnt) ? __expf(e) : 0.f;
        float ws = w;
#pragma unroll
        for (int off = 1; off < 64; off <<= 1) ws += __shfl_xor(ws, off);
        den += ws;
        auto loadrow = [&](int j) -> float {
            j = (j < cnt) ? j : (cnt - 1);
            int sp = __shfl(s, j);
            return hin[(size_t)sp * 64 + lane];
        };
        float p0 = loadrow(0), p1 = loadrow(1), p2 = loadrow(2), p3 = loadrow(3);
        float p4 = loadrow(4), p5 = loadrow(5), p6 = loadrow(6), p7 = loadrow(7);
        for (int j = 0; j < cnt; j += 8) {
            float q0 = p0, q1 = p1, q2 = p2, q3 = p3;
            float q4 = p4, q5 = p5, q6 = p6, q7 = p7;
            p0 = loadrow(j + 8);  p1 = loadrow(j + 9);
            p2 = loadrow(j + 10); p3 = loadrow(j + 11);
            p4 = loadrow(j + 12); p5 = loadrow(j + 13);
            p6 = loadrow(j + 14); p7 = loadrow(j + 15);
            acc = fmaf(__shfl(w, j), q0, acc);
            acc = fmaf(__shfl(w, j + 1), q1, acc);
            acc = fmaf(__shfl(w, j + 2), q2, acc);
            acc = fmaf(__shfl(w, j + 3), q3, acc);
            acc = fmaf(__shfl(w, j + 4), q4, acc);
            acc = fmaf(__shfl(w, j + 5), q5, acc);
            acc = fmaf(__shfl(w, j + 6), q6, acc);
            acc = fmaf(__shfl(w, j + 7), q7, acc);
        }
    }
    float o = acc / den + bias[lane];
    o = (o > 0.f) ? o : expm1f(o);               // ELU
    gout[(size_t)d * 64 + lane] = o;
    float v = o * wp[lane];
#pragma unroll
    for (int off = 32; off; off >>= 1) v += __shfl_xor(v, off);
    if (lane == 0) attn[d] = 1.f / (1.f + __expf(-(v + bp[0])));
}

// ---------------- parallel segmented pooling (batch is sorted) --------------
__global__ void pool_partial_k(const float* __restrict__ g3, const float* __restrict__ attn,
                               const int* __restrict__ batch, int n, float* __restrict__ sums) {
    int wid = blockIdx.x * (blockDim.x >> 6) + (threadIdx.x >> 6);
    int lane = threadIdx.x & 63;
    int nwaves = gridDim.x * (blockDim.x >> 6);
    int per = (n + nwaves - 1) / nwaves;
    int i0 = wid * per;
    int i1 = i0 + per;
    if (i1 > n) i1 = n;
    if (i0 >= i1) return;
    int cur = batch[i0];
    float acc = 0.f;
    for (int i = i0; i < i1; ++i) {
        int b = batch[i];
        if (b != cur) {
            atomicAdd(&sums[cur * 64 + lane], acc);
            acc = 0.f;
            cur = b;
        }
        acc += g3[(size_t)i * 64 + lane] * attn[i];
    }
    atomicAdd(&sums[cur * 64 + lane], acc);
}

// ---------------- final regressor: one block, wave per graph ----------------
__global__ void regress_k(const float* __restrict__ sums, const int* __restrict__ batch, int n,
                          const float* __restrict__ wr, const float* __restrict__ br,
                          float* __restrict__ out, int B) {
    int b = threadIdx.x >> 6;
    int lane = threadIdx.x & 63;
    if (b >= B) return;
    int lo = 0, hi = n;
    while (lo < hi) { int mid = (lo + hi) >> 1; if (batch[mid] < b) lo = mid + 1; else hi = mid; }
    int seg_lo = lo;
    lo = 0; hi = n;
    while (lo < hi) { int mid = (lo + hi) >> 1; if (batch[mid] < b + 1) lo = mid + 1; else hi = mid; }
    float cnt = (float)(lo - seg_lo);
    if (cnt < 1.f) cnt = 1.f;
    float v = (sums[b * 64 + lane] / cnt) * wr[lane];
#pragma unroll
    for (int off = 32; off; off >>= 1) v += __shfl_xor(v, off);
    if (lane == 0) out[b] = v + br[0];
}

// ---------------------------------------------------------------------------
extern "C" void kernel_launch(void* const* d_in, const int* in_sizes, int n_in,
                              void* d_out, int out_size, void* d_ws, size_t ws_size,
                              hipStream_t stream) {
    const float* x   = (const float*)d_in[0];
    const int*   ei  = (const int*)d_in[1];
    const int*   bat = (const int*)d_in[2];
    const float* W1  = (const float*)d_in[3];
    const float* as1 = (const float*)d_in[4];
    const float* ad1 = (const float*)d_in[5];
    const float* b1  = (const float*)d_in[6];
    const float* W2  = (const float*)d_in[7];
    const float* as2 = (const float*)d_in[8];
    const float* ad2 = (const float*)d_in[9];
    const float* b2  = (const float*)d_in[10];
    const float* W3  = (const float*)d_in[11];
    const float* as3 = (const float*)d_in[12];
    const float* ad3 = (const float*)d_in[13];
    const float* b3  = (const float*)d_in[14];
    const float* wp  = (const float*)d_in[15];
    const float* bp  = (const float*)d_in[16];
    const float* wr  = (const float*)d_in[17];
    const float* br  = (const float*)d_in[18];
    float* out = (float*)d_out;

    const int N    = in_sizes[2];          // 20000
    const int E    = in_sizes[1] / 2;      // 320000
    const int DIN  = in_sizes[0] / N;      // 128
    const int Etot = E + N;
    const int Bc   = out_size;             // 16

    char* ws = (char*)d_ws;
    size_t off = 0;
    auto alloc = [&](size_t bytes) {
        void* p = ws + off;
        off = (off + bytes + 255) & ~(size_t)255;
        return p;
    };
    int*   deg    = (int*)alloc((size_t)N * 4);
    int*   rowptr = (int*)alloc((size_t)(N + 1) * 4);
    int*   cursor = (int*)alloc((size_t)N * 4);
    int*   srcs   = (int*)alloc((size_t)Etot * 4);
    float* bufA   = (float*)alloc((size_t)N * 256 * 4);     // GEMM out h (head-major)
    u16*   Ahi    = (u16*)alloc((size_t)N * 256 * 2);       // x/g split hi
    u16*   Alo    = (u16*)alloc((size_t)N * 256 * 2);       // x/g split lo
    float* h3     = (float*)alloc((size_t)N * 64 * 4);
    float* g3     = (float*)alloc((size_t)N * 64 * 4);
    float* esrc   = (float*)alloc((size_t)N * 4 * 4);
    float* edst   = (float*)alloc((size_t)N * 4 * 4);
    float* attn   = (float*)alloc((size_t)N * 4);
    float* sums   = (float*)alloc((size_t)Bc * 64 * 4);
    u16*   w1hi   = (u16*)alloc((size_t)256 * DIN * 2);
    u16*   w1lo   = (u16*)alloc((size_t)256 * DIN * 2);
    u16*   w2hi   = (u16*)alloc((size_t)256 * 256 * 2);
    u16*   w2lo   = (u16*)alloc((size_t)256 * 256 * 2);
    u16*   w3hi   = (u16*)alloc((size_t)64 * 256 * 2);
    u16*   w3lo   = (u16*)alloc((size_t)64 * 256 * 2);
    (void)ws_size;

    // CSR build (shared by all layers)
    hipMemsetAsync(deg, 0, (size_t)N * 4, stream);
    int eb = (Etot + 255) / 256;
    edge_hist_k<<<eb, 256, 0, stream>>>(ei, E, N, deg);
    scan_excl_k<<<1, 1024, 0, stream>>>(deg, rowptr, cursor, N);
    edge_scatter_k<<<eb, 256, 0, stream>>>(ei, E, N, cursor, srcs);

    // weight splits (transposed) + x split
    splitT_bf16_k<<<(DIN * 256 + 255) / 256, 256, 0, stream>>>(W1, w1hi, w1lo, DIN, 256);
    splitT_bf16_k<<<(256 * 256 + 255) / 256, 256, 0, stream>>>(W2, w2hi, w2lo, 256, 256);
    splitT_bf16_k<<<(256 * 64 + 255) / 256, 256, 0, stream>>>(W3, w3hi, w3lo, 256, 64);
    split_bf16_k<<<(N * DIN / 4 + 255) / 256, 256, 0, stream>>>(x, Ahi, Alo, N * DIN / 4);

    const int mb = (N + 63) / 64;          // 313
    int nb4 = (N + 3) / 4;
    dim3 agg_grid(nb4, 4);

    // Layer 1: DIN -> (4,64) concat      (BN=128 -> 2 n-tiles)
    gemm_lds_k<2><<<mb * 2, 256, 0, stream>>>(Ahi, Alo, w1hi, w1lo, bufA, as1, ad1, esrc, edst, N, 256, DIN);
    gat_aggregate_hm_k<<<agg_grid, 256, 0, stream>>>(bufA, esrc, edst, rowptr, srcs, b1, Ahi, Alo, N);

    // Layer 2: 256 -> (4,64) concat
    gemm_lds_k<2><<<mb * 2, 256, 0, stream>>>(Ahi, Alo, w2hi, w2lo, bufA, as2, ad2, esrc, edst, N, 256, 256);
    gat_aggregate_hm_k<<<agg_grid, 256, 0, stream>>>(bufA, esrc, edst, rowptr, srcs, b2, Ahi, Alo, N);

    // Layer 3: 256 -> (1,64) mean + fused node-attention gate   (BN=64)
    gemm_lds_k<1><<<mb, 256, 0, stream>>>(Ahi, Alo, w3hi, w3lo, h3, as3, ad3, esrc, edst, N, 64, 256);
    gat_aggregate1_attn_k<<<nb4, 256, 0, stream>>>(h3, esrc, edst, rowptr, srcs, b3, wp, bp, g3, attn, N);

    // Attention pool + regressor (parallel)
    hipMemsetAsync(sums, 0, (size_t)Bc * 64 * 4, stream);
    pool_partial_k<<<256, 256, 0, stream>>>(g3, attn, bat, N, sums);
    regress_k<<<1, 1024, 0, stream>>>(sums, bat, N, wr, br, out, Bc);
}

// Round 10
// 278.512 us; speedup vs baseline: 1.0219x; 1.0219x over previous
//
#include <hip/hip_runtime.h>

// ---------------------------------------------------------------------------
// GAT (3 layers) + attention pooling + regressor.
// GEMMs: split-bf16 MFMA (a_hi+a_lo, 3 products, f32 accum), A staged in LDS
// via global_load_lds; attn scores fused into GEMM epilogue; h stored
// HEAD-MAJOR [H][N][64] so the aggregate gathers from a 5.1MB/head set.
// Aggregates: one wave per (dst,head); 4 edges per wave-instruction
// (lane = edge_sub x chan_quad, float4 rows), batched weights.
// N=20000 nodes, E=320000 edges (+N self loops), H=4 heads, C=64, B=16 graphs.
// ---------------------------------------------------------------------------

typedef unsigned short u16;
typedef __attribute__((ext_vector_type(8))) short bf16x8;
typedef __attribute__((ext_vector_type(4))) float f32x4;

__device__ __forceinline__ u16 bf16rn(float x) {
    unsigned u = __float_as_uint(x);
    u += 0x7FFFu + ((u >> 16) & 1u);
    return (u16)(u >> 16);
}
__device__ __forceinline__ float bf16f(u16 h) {
    return __uint_as_float(((unsigned)h) << 16);
}

__device__ __forceinline__ void gload16(const u16* g, u16* l) {
    __builtin_amdgcn_global_load_lds(
        (const __attribute__((address_space(1))) unsigned int*)g,
        (__attribute__((address_space(3))) unsigned int*)l, 16, 0, 0);
}

// ---------------- CSR-by-destination build ----------------
__global__ void edge_hist_k(const int* __restrict__ ei, int E, int n, int* __restrict__ deg) {
    int i = blockIdx.x * blockDim.x + threadIdx.x;
    if (i >= E + n) return;
    int dst = (i < E) ? ei[E + i] : (i - E);   // self-loop for i >= E
    atomicAdd(&deg[dst], 1);
}

__global__ __launch_bounds__(1024) void scan_excl_k(const int* __restrict__ deg, int* __restrict__ rowptr,
                                                    int* __restrict__ cursor, int n) {
    __shared__ int part[1024];
    int tid = threadIdx.x;
    int chunk = (n + 1023) / 1024;
    int lo = tid * chunk;
    int hi = lo + chunk;
    if (lo > n) lo = n;
    if (hi > n) hi = n;
    int s = 0;
    for (int i = lo; i < hi; ++i) s += deg[i];
    part[tid] = s;
    __syncthreads();
    for (int off = 1; off < 1024; off <<= 1) {
        int v = (tid >= off) ? part[tid - off] : 0;
        __syncthreads();
        part[tid] += v;
        __syncthreads();
    }
    int run = (tid == 0) ? 0 : part[tid - 1];
    for (int i = lo; i < hi; ++i) {
        rowptr[i] = run;
        cursor[i] = run;
        run += deg[i];
    }
    if (tid == 1023) rowptr[n] = run;
}

__global__ void edge_scatter_k(const int* __restrict__ ei, int E, int n,
                               int* __restrict__ cursor, int* __restrict__ srcs) {
    int i = blockIdx.x * blockDim.x + threadIdx.x;
    if (i >= E + n) return;
    int src, dst;
    if (i < E) { src = ei[i]; dst = ei[E + i]; }
    else       { src = i - E; dst = src; }
    int pos = atomicAdd(&cursor[dst], 1);
    srcs[pos] = src;
}

// ---------------- bf16 split conversions ----------------
__global__ void split_bf16_k(const float* __restrict__ in, u16* __restrict__ hi,
                             u16* __restrict__ lo, int n4) {
    int i = blockIdx.x * 256 + threadIdx.x;
    if (i >= n4) return;
    float4 v = reinterpret_cast<const float4*>(in)[i];
    u16 hx = bf16rn(v.x), hy = bf16rn(v.y), hz = bf16rn(v.z), hw = bf16rn(v.w);
    ushort4 H = make_ushort4(hx, hy, hz, hw);
    ushort4 L = make_ushort4(bf16rn(v.x - bf16f(hx)), bf16rn(v.y - bf16f(hy)),
                             bf16rn(v.z - bf16f(hz)), bf16rn(v.w - bf16f(hw)));
    reinterpret_cast<ushort4*>(hi)[i] = H;
    reinterpret_cast<ushort4*>(lo)[i] = L;
}

// W[K][Nn] row-major -> transposed split Wt[Nn][K] (hi, lo)
__global__ void splitT_bf16_k(const float* __restrict__ W, u16* __restrict__ thi,
                              u16* __restrict__ tlo, int K, int Nn) {
    int idx = blockIdx.x * 256 + threadIdx.x;
    if (idx >= K * Nn) return;
    int k = idx / Nn, nn = idx - k * Nn;
    float v = W[idx];
    u16 h = bf16rn(v);
    u16 l = bf16rn(v - bf16f(h));
    thi[(size_t)nn * K + k] = h;
    tlo[(size_t)nn * K + k] = l;
}

// ---------------- split-bf16 MFMA GEMM, LDS-staged A, fused attn scores ----
// C emitted HEAD-MAJOR: C[((col>>6)*M + row)*64 + (col&63)].
// Epilogue also emits esrc/edst [M][Nn/64]: per-row dot with a_src/a_dst.
template <int NF>
__global__ __launch_bounds__(256) void gemm_lds_k(
        const u16* __restrict__ Ahi, const u16* __restrict__ Alo,
        const u16* __restrict__ Bthi, const u16* __restrict__ Btlo,
        float* __restrict__ C,
        const float* __restrict__ a_src, const float* __restrict__ a_dst,
        float* __restrict__ esrc, float* __restrict__ edst,
        int M, int Nn, int K) {
    __shared__ u16 Ah[2][4][64 * 8];   // [buf][kg][row*8]
    __shared__ u16 Al[2][4][64 * 8];
    const int mb = (M + 63) >> 6;
    const int mi = blockIdx.x % mb;
    const int ni = blockIdx.x / mb;
    const int m0 = mi * 64;
    const int n0 = ni * (NF * 64);
    const int tid = threadIdx.x;
    const int wv = tid >> 6;
    const int lane = tid & 63;
    const int rr = lane & 15;
    const int kg = lane >> 4;

    int srow = m0 + lane; if (srow > M - 1) srow = M - 1;
    const u16* sh = Ahi + (size_t)srow * K + wv * 8;
    const u16* sl = Alo + (size_t)srow * K + wv * 8;

    const u16* pbh[NF];
    const u16* pbl[NF];
#pragma unroll
    for (int nf = 0; nf < NF; ++nf) {
        int col = n0 + (wv * NF + nf) * 16 + rr;
        pbh[nf] = Bthi + (size_t)col * K + kg * 8;
        pbl[nf] = Btlo + (size_t)col * K + kg * 8;
    }

    f32x4 acc[4][NF];
#pragma unroll
    for (int mf = 0; mf < 4; ++mf)
#pragma unroll
        for (int nf = 0; nf < NF; ++nf) acc[mf][nf] = (f32x4){0.f, 0.f, 0.f, 0.f};

    bf16x8 bhc[NF], blc[NF], bhn[NF], bln[NF];
#pragma unroll
    for (int nf = 0; nf < NF; ++nf) {
        bhc[nf] = *reinterpret_cast<const bf16x8*>(pbh[nf]);
        blc[nf] = *reinterpret_cast<const bf16x8*>(pbl[nf]);
    }
    gload16(sh, &Ah[0][wv][0]);
    gload16(sl, &Al[0][wv][0]);
    __syncthreads();

    const int NT = K >> 5;
    for (int t = 0; t < NT; ++t) {
        const int cur = t & 1;
        if (t + 1 < NT) {
            const int kc = (t + 1) << 5;
#pragma unroll
            for (int nf = 0; nf < NF; ++nf) {
                bhn[nf] = *reinterpret_cast<const bf16x8*>(pbh[nf] + kc);
                bln[nf] = *reinterpret_cast<const bf16x8*>(pbl[nf] + kc);
            }
            gload16(sh + kc, &Ah[cur ^ 1][wv][0]);
            gload16(sl + kc, &Al[cur ^ 1][wv][0]);
        }
        bf16x8 ah[4], al[4];
#pragma unroll
        for (int mf = 0; mf < 4; ++mf) {
            ah[mf] = *reinterpret_cast<const bf16x8*>(&Ah[cur][kg][(mf * 16 + rr) * 8]);
            al[mf] = *reinterpret_cast<const bf16x8*>(&Al[cur][kg][(mf * 16 + rr) * 8]);
        }
#pragma unroll
        for (int mf = 0; mf < 4; ++mf)
#pragma unroll
            for (int nf = 0; nf < NF; ++nf) {
                acc[mf][nf] = __builtin_amdgcn_mfma_f32_16x16x32_bf16(ah[mf], bhc[nf], acc[mf][nf], 0, 0, 0);
                acc[mf][nf] = __builtin_amdgcn_mfma_f32_16x16x32_bf16(ah[mf], blc[nf], acc[mf][nf], 0, 0, 0);
                acc[mf][nf] = __builtin_amdgcn_mfma_f32_16x16x32_bf16(al[mf], bhc[nf], acc[mf][nf], 0, 0, 0);
            }
#pragma unroll
        for (int nf = 0; nf < NF; ++nf) { bhc[nf] = bhn[nf]; blc[nf] = bln[nf]; }
        __syncthreads();
    }

    // ---- C store (head-major) ----
#pragma unroll
    for (int mf = 0; mf < 4; ++mf)
#pragma unroll
        for (int nf = 0; nf < NF; ++nf) {
            int col = n0 + (wv * NF + nf) * 16 + rr;
            float* cb = C + ((size_t)(col >> 6) * M) * 64 + (col & 63);
#pragma unroll
            for (int rg = 0; rg < 4; ++rg) {
                int row = m0 + mf * 16 + kg * 4 + rg;
                if (row < M) cb[(size_t)row * 64] = acc[mf][nf][rg];
            }
        }

    // ---- fused attention scores: per-row dot with a_src / a_dst ----
    float asv[NF], adv[NF];
#pragma unroll
    for (int nf = 0; nf < NF; ++nf) {
        int col = n0 + (wv * NF + nf) * 16 + rr;
        asv[nf] = a_src[col];
        adv[nf] = a_dst[col];
    }
    float ps[4][4], pd[4][4];   // [mf][rg]
#pragma unroll
    for (int mf = 0; mf < 4; ++mf)
#pragma unroll
        for (int rg = 0; rg < 4; ++rg) {
            float s = 0.f, dvv = 0.f;
#pragma unroll
            for (int nf = 0; nf < NF; ++nf) {
                s = fmaf(acc[mf][nf][rg], asv[nf], s);
                dvv = fmaf(acc[mf][nf][rg], adv[nf], dvv);
            }
#pragma unroll
            for (int off = 1; off < 16; off <<= 1) {
                s += __shfl_xor(s, off);
                dvv += __shfl_xor(dvv, off);
            }
            ps[mf][rg] = s;
            pd[mf][rg] = dvv;
        }
    // cross-wave combine via LDS (reuse Ah; all reads of it completed)
    float* sm_src = (float*)&Ah[0][0][0];     // [4 waves][64 rows]
    float* sm_dst = sm_src + 256;
    if (rr == 0) {
#pragma unroll
        for (int mf = 0; mf < 4; ++mf)
#pragma unroll
            for (int rg = 0; rg < 4; ++rg) {
                int rl = mf * 16 + kg * 4 + rg;
                sm_src[wv * 64 + rl] = ps[mf][rg];
                sm_dst[wv * 64 + rl] = pd[mf][rg];
            }
    }
    __syncthreads();
    if (tid < 64) {
        int row = m0 + tid;
        if (row < M) {
            const int HTOT = Nn >> 6;
            constexpr int WPH = 4 / NF;        // waves per head
#pragma unroll
            for (int hl = 0; hl < NF; ++hl) {
                float es = 0.f, edv = 0.f;
#pragma unroll
                for (int w = 0; w < WPH; ++w) {
                    es += sm_src[(hl * WPH + w) * 64 + tid];
                    edv += sm_dst[(hl * WPH + w) * 64 + tid];
                }
                int hg = ni * NF + hl;
                esrc[(size_t)row * HTOT + hg] = es;
                edst[(size_t)row * HTOT + hg] = edv;
            }
        }
    }
}

// ---------------- GAT aggregation, head-split, 4-edges-per-instruction -----
// hm head-major [4][n][64]. Wave per (dst,head); lane = (es=lane>>4, cq=lane&15).
// One float4 load covers 4 rows x 16 quads; weights batched (1 exp / 64 edges).
__global__ __launch_bounds__(256) void gat_aggregate_hm_k(
        const float* __restrict__ hm, const float* __restrict__ esrc,
        const float* __restrict__ edst, const int* __restrict__ rowptr,
        const int* __restrict__ srcs, const float* __restrict__ bias,
        u16* __restrict__ ghi, u16* __restrict__ glo, int n) {
    int d = blockIdx.x * 4 + (threadIdx.x >> 6);
    int lane = threadIdx.x & 63;
    int hh = blockIdx.y;                        // head
    if (d >= n) return;
    const float* hbase = hm + (size_t)hh * n * 64;
    const int es = lane >> 4;                   // edge sub-slot 0..3
    const int cq = lane & 15;                   // channel quad
    float ed = edst[d * 4 + hh];
    int lo = rowptr[d], hi = rowptr[d + 1];
    float4 acc = make_float4(0.f, 0.f, 0.f, 0.f);
    float den = 0.f;
    for (int base = lo; base < hi; base += 64) {
        int cnt = min(64, hi - base);
        int idx = base + lane;
        int s = srcs[(idx < hi) ? idx : lo];
        float e = esrc[s * 4 + hh] + ed;
        e = (e >= 0.f) ? e : 0.2f * e;          // leaky_relu(0.2)
        float w = (lane < cnt) ? __expf(e) : 0.f;
        float ws = w;
#pragma unroll
        for (int off = 1; off < 64; off <<= 1) ws += __shfl_xor(ws, off);
        den += ws;
        // ---- multiply: 4 edges per instruction, 4-group prefetch ----
        auto loadq = [&](int j) -> float4 {     // j = group base (multiple of 4)
            int jj = j + es;
            jj = (jj < cnt) ? jj : (cnt - 1);   // clamped addr; weight is 0 there
            int sp = __shfl(s, jj);
            return *reinterpret_cast<const float4*>(&hbase[(size_t)sp * 64 + cq * 4]);
        };
        auto wsel = [&](int j) -> float {       // weight of this lane's edge
            int jj = j + es;
            float v = __shfl(w, jj & 63);
            return (jj < cnt) ? v : 0.f;
        };
        float4 p0 = loadq(0), p1 = loadq(4), p2 = loadq(8), p3 = loadq(12);
        for (int j = 0; j < cnt; j += 16) {
            float4 q0 = p0, q1 = p1, q2 = p2, q3 = p3;
            p0 = loadq(j + 16); p1 = loadq(j + 20);
            p2 = loadq(j + 24); p3 = loadq(j + 28);
            float w0 = wsel(j), w1 = wsel(j + 4), w2 = wsel(j + 8), w3 = wsel(j + 12);
            acc.x = fmaf(w0, q0.x, acc.x); acc.y = fmaf(w0, q0.y, acc.y);
            acc.z = fmaf(w0, q0.z, acc.z); acc.w = fmaf(w0, q0.w, acc.w);
            acc.x = fmaf(w1, q1.x, acc.x); acc.y = fmaf(w1, q1.y, acc.y);
            acc.z = fmaf(w1, q1.z, acc.z); acc.w = fmaf(w1, q1.w, acc.w);
            acc.x = fmaf(w2, q2.x, acc.x); acc.y = fmaf(w2, q2.y, acc.y);
            acc.z = fmaf(w2, q2.z, acc.z); acc.w = fmaf(w2, q2.w, acc.w);
            acc.x = fmaf(w3, q3.x, acc.x); acc.y = fmaf(w3, q3.y, acc.y);
            acc.z = fmaf(w3, q3.z, acc.z); acc.w = fmaf(w3, q3.w, acc.w);
        }
    }
    // combine the 4 edge sub-slots (lanes differing in bits 4,5)
    acc.x += __shfl_xor(acc.x, 16); acc.x += __shfl_xor(acc.x, 32);
    acc.y += __shfl_xor(acc.y, 16); acc.y += __shfl_xor(acc.y, 32);
    acc.z += __shfl_xor(acc.z, 16); acc.z += __shfl_xor(acc.z, 32);
    acc.w += __shfl_xor(acc.w, 16); acc.w += __shfl_xor(acc.w, 32);
    if (es == 0) {
        int c0 = hh * 64 + cq * 4;
        float inv = 1.f / den;
        float4 bv = *reinterpret_cast<const float4*>(&bias[c0]);
        float4 o;
        o.x = acc.x * inv + bv.x;
        o.y = acc.y * inv + bv.y;
        o.z = acc.z * inv + bv.z;
        o.w = acc.w * inv + bv.w;
        o.x = (o.x > 0.f) ? o.x : expm1f(o.x);   // ELU
        o.y = (o.y > 0.f) ? o.y : expm1f(o.y);
        o.z = (o.z > 0.f) ? o.z : expm1f(o.z);
        o.w = (o.w > 0.f) ? o.w : expm1f(o.w);
        u16 hx = bf16rn(o.x), hy = bf16rn(o.y), hz = bf16rn(o.z), hw = bf16rn(o.w);
        ushort4 H = make_ushort4(hx, hy, hz, hw);
        ushort4 L = make_ushort4(bf16rn(o.x - bf16f(hx)), bf16rn(o.y - bf16f(hy)),
                                 bf16rn(o.z - bf16f(hz)), bf16rn(o.w - bf16f(hw)));
        *reinterpret_cast<ushort4*>(&ghi[(size_t)d * 256 + c0]) = H;
        *reinterpret_cast<ushort4*>(&glo[(size_t)d * 256 + c0]) = L;
    }
}

// ---------------- layer-3 aggregate (1 head) fused with node attn gate ------
// Same 4-edges-per-instruction structure; full 64-ch dot for the gate.
__global__ __launch_bounds__(256) void gat_aggregate1_attn_k(
        const float* __restrict__ hin, const float* __restrict__ esrc,
        const float* __restrict__ edst, const int* __restrict__ rowptr,
        const int* __restrict__ srcs, const float* __restrict__ bias,
        const float* __restrict__ wp, const float* __restrict__ bp,
        float* __restrict__ gout, float* __restrict__ attn, int n) {
    int d = blockIdx.x * 4 + (threadIdx.x >> 6);
    int lane = threadIdx.x & 63;
    if (d >= n) return;
    const int es = lane >> 4;
    const int cq = lane & 15;
    float ed = edst[d];
    int lo = rowptr[d], hi = rowptr[d + 1];
    float4 acc = make_float4(0.f, 0.f, 0.f, 0.f);
    float den = 0.f;
    for (int base = lo; base < hi; base += 64) {
        int cnt = min(64, hi - base);
        int idx = base + lane;
        int s = srcs[(idx < hi) ? idx : lo];
        float e = esrc[s] + ed;
        e = (e >= 0.f) ? e : 0.2f * e;
        float w = (lane < cnt) ? __expf(e) : 0.f;
        float ws = w;
#pragma unroll
        for (int off = 1; off < 64; off <<= 1) ws += __shfl_xor(ws, off);
        den += ws;
        auto loadq = [&](int j) -> float4 {
            int jj = j + es;
            jj = (jj < cnt) ? jj : (cnt - 1);
            int sp = __shfl(s, jj);
            return *reinterpret_cast<const float4*>(&hin[(size_t)sp * 64 + cq * 4]);
        };
        auto wsel = [&](int j) -> float {
            int jj = j + es;
            float v = __shfl(w, jj & 63);
            return (jj < cnt) ? v : 0.f;
        };
        float4 p0 = loadq(0), p1 = loadq(4), p2 = loadq(8), p3 = loadq(12);
        for (int j = 0; j < cnt; j += 16) {
            float4 q0 = p0, q1 = p1, q2 = p2, q3 = p3;
            p0 = loadq(j + 16); p1 = loadq(j + 20);
            p2 = loadq(j + 24); p3 = loadq(j + 28);
            float w0 = wsel(j), w1 = wsel(j + 4), w2 = wsel(j + 8), w3 = wsel(j + 12);
            acc.x = fmaf(w0, q0.x, acc.x); acc.y = fmaf(w0, q0.y, acc.y);
            acc.z = fmaf(w0, q0.z, acc.z); acc.w = fmaf(w0, q0.w, acc.w);
            acc.x = fmaf(w1, q1.x, acc.x); acc.y = fmaf(w1, q1.y, acc.y);
            acc.z = fmaf(w1, q1.z, acc.z); acc.w = fmaf(w1, q1.w, acc.w);
            acc.x = fmaf(w2, q2.x, acc.x); acc.y = fmaf(w2, q2.y, acc.y);
            acc.z = fmaf(w2, q2.z, acc.z); acc.w = fmaf(w2, q2.w, acc.w);
            acc.x = fmaf(w3, q3.x, acc.x); acc.y = fmaf(w3, q3.y, acc.y);
            acc.z = fmaf(w3, q3.z, acc.z); acc.w = fmaf(w3, q3.w, acc.w);
        }
    }
    acc.x += __shfl_xor(acc.x, 16); acc.x += __shfl_xor(acc.x, 32);
    acc.y += __shfl_xor(acc.y, 16); acc.y += __shfl_xor(acc.y, 32);
    acc.z += __shfl_xor(acc.z, 16); acc.z += __shfl_xor(acc.z, 32);
    acc.w += __shfl_xor(acc.w, 16); acc.w += __shfl_xor(acc.w, 32);
    int c0 = cq * 4;
    float inv = 1.f / den;
    float4 bv = *reinterpret_cast<const float4*>(&bias[c0]);
    float4 o;
    o.x = acc.x * inv + bv.x;
    o.y = acc.y * inv + bv.y;
    o.z = acc.z * inv + bv.z;
    o.w = acc.w * inv + bv.w;
    o.x = (o.x > 0.f) ? o.x : expm1f(o.x);       // ELU
    o.y = (o.y > 0.f) ? o.y : expm1f(o.y);
    o.z = (o.z > 0.f) ? o.z : expm1f(o.z);
    o.w = (o.w > 0.f) ? o.w : expm1f(o.w);
    if (es == 0)
        *reinterpret_cast<float4*>(&gout[(size_t)d * 64 + c0]) = o;
    // node attention gate: full 64-ch dot (cq lanes each hold 4 channels)
    float4 wv4 = *reinterpret_cast<const float4*>(&wp[c0]);
    float v = o.x * wv4.x + o.y * wv4.y + o.z * wv4.z + o.w * wv4.w;
#pragma unroll
    for (int off = 1; off < 16; off <<= 1) v += __shfl_xor(v, off);
    if (lane == 0) attn[d] = 1.f / (1.f + __expf(-(v + bp[0])));
}

// ---------------- parallel segmented pooling (batch is sorted) --------------
__global__ void pool_partial_k(const float* __restrict__ g3, const float* __restrict__ attn,
                               const int* __restrict__ batch, int n, float* __restrict__ sums) {
    int wid = blockIdx.x * (blockDim.x >> 6) + (threadIdx.x >> 6);
    int lane = threadIdx.x & 63;
    int nwaves = gridDim.x * (blockDim.x >> 6);
    int per = (n + nwaves - 1) / nwaves;
    int i0 = wid * per;
    int i1 = i0 + per;
    if (i1 > n) i1 = n;
    if (i0 >= i1) return;
    int cur = batch[i0];
    float acc = 0.f;
    for (int i = i0; i < i1; ++i) {
        int b = batch[i];
        if (b != cur) {
            atomicAdd(&sums[cur * 64 + lane], acc);
            acc = 0.f;
            cur = b;
        }
        acc += g3[(size_t)i * 64 + lane] * attn[i];
    }
    atomicAdd(&sums[cur * 64 + lane], acc);
}

// ---------------- final regressor: one block, wave per graph ----------------
__global__ void regress_k(const float* __restrict__ sums, const int* __restrict__ batch, int n,
                          const float* __restrict__ wr, const float* __restrict__ br,
                          float* __restrict__ out, int B) {
    int b = threadIdx.x >> 6;
    int lane = threadIdx.x & 63;
    if (b >= B) return;
    int lo = 0, hi = n;
    while (lo < hi) { int mid = (lo + hi) >> 1; if (batch[mid] < b) lo = mid + 1; else hi = mid; }
    int seg_lo = lo;
    lo = 0; hi = n;
    while (lo < hi) { int mid = (lo + hi) >> 1; if (batch[mid] < b + 1) lo = mid + 1; else hi = mid; }
    float cnt = (float)(lo - seg_lo);
    if (cnt < 1.f) cnt = 1.f;
    float v = (sums[b * 64 + lane] / cnt) * wr[lane];
#pragma unroll
    for (int off = 32; off; off >>= 1) v += __shfl_xor(v, off);
    if (lane == 0) out[b] = v + br[0];
}

// ---------------------------------------------------------------------------
extern "C" void kernel_launch(void* const* d_in, const int* in_sizes, int n_in,
                              void* d_out, int out_size, void* d_ws, size_t ws_size,
                              hipStream_t stream) {
    const float* x   = (const float*)d_in[0];
    const int*   ei  = (const int*)d_in[1];
    const int*   bat = (const int*)d_in[2];
    const float* W1  = (const float*)d_in[3];
    const float* as1 = (const float*)d_in[4];
    const float* ad1 = (const float*)d_in[5];
    const float* b1  = (const float*)d_in[6];
    const float* W2  = (const float*)d_in[7];
    const float* as2 = (const float*)d_in[8];
    const float* ad2 = (const float*)d_in[9];
    const float* b2  = (const float*)d_in[10];
    const float* W3  = (const float*)d_in[11];
    const float* as3 = (const float*)d_in[12];
    const float* ad3 = (const float*)d_in[13];
    const float* b3  = (const float*)d_in[14];
    const float* wp  = (const float*)d_in[15];
    const float* bp  = (const float*)d_in[16];
    const float* wr  = (const float*)d_in[17];
    const float* br  = (const float*)d_in[18];
    float* out = (float*)d_out;

    const int N    = in_sizes[2];          // 20000
    const int E    = in_sizes[1] / 2;      // 320000
    const int DIN  = in_sizes[0] / N;      // 128
    const int Etot = E + N;
    const int Bc   = out_size;             // 16

    char* ws = (char*)d_ws;
    size_t off = 0;
    auto alloc = [&](size_t bytes) {
        void* p = ws + off;
        off = (off + bytes + 255) & ~(size_t)255;
        return p;
    };
    int*   deg    = (int*)alloc((size_t)N * 4);
    int*   rowptr = (int*)alloc((size_t)(N + 1) * 4);
    int*   cursor = (int*)alloc((size_t)N * 4);
    int*   srcs   = (int*)alloc((size_t)Etot * 4);
    float* bufA   = (float*)alloc((size_t)N * 256 * 4);     // GEMM out h (head-major)
    u16*   Ahi    = (u16*)alloc((size_t)N * 256 * 2);       // x/g split hi
    u16*   Alo    = (u16*)alloc((size_t)N * 256 * 2);       // x/g split lo
    float* h3     = (float*)alloc((size_t)N * 64 * 4);
    float* g3     = (float*)alloc((size_t)N * 64 * 4);
    float* esrc   = (float*)alloc((size_t)N * 4 * 4);
    float* edst   = (float*)alloc((size_t)N * 4 * 4);
    float* attn   = (float*)alloc((size_t)N * 4);
    float* sums   = (float*)alloc((size_t)Bc * 64 * 4);
    u16*   w1hi   = (u16*)alloc((size_t)256 * DIN * 2);
    u16*   w1lo   = (u16*)alloc((size_t)256 * DIN * 2);
    u16*   w2hi   = (u16*)alloc((size_t)256 * 256 * 2);
    u16*   w2lo   = (u16*)alloc((size_t)256 * 256 * 2);
    u16*   w3hi   = (u16*)alloc((size_t)64 * 256 * 2);
    u16*   w3lo   = (u16*)alloc((size_t)64 * 256 * 2);
    (void)ws_size;

    // CSR build (shared by all layers)
    hipMemsetAsync(deg, 0, (size_t)N * 4, stream);
    int eb = (Etot + 255) / 256;
    edge_hist_k<<<eb, 256, 0, stream>>>(ei, E, N, deg);
    scan_excl_k<<<1, 1024, 0, stream>>>(deg, rowptr, cursor, N);
    edge_scatter_k<<<eb, 256, 0, stream>>>(ei, E, N, cursor, srcs);

    // weight splits (transposed) + x split
    splitT_bf16_k<<<(DIN * 256 + 255) / 256, 256, 0, stream>>>(W1, w1hi, w1lo, DIN, 256);
    splitT_bf16_k<<<(256 * 256 + 255) / 256, 256, 0, stream>>>(W2, w2hi, w2lo, 256, 256);
    splitT_bf16_k<<<(256 * 64 + 255) / 256, 256, 0, stream>>>(W3, w3hi, w3lo, 256, 64);
    split_bf16_k<<<(N * DIN / 4 + 255) / 256, 256, 0, stream>>>(x, Ahi, Alo, N * DIN / 4);

    const int mb = (N + 63) / 64;          // 313
    int nb4 = (N + 3) / 4;
    dim3 agg_grid(nb4, 4);

    // Layer 1: DIN -> (4,64) concat      (BN=128 -> 2 n-tiles)
    gemm_lds_k<2><<<mb * 2, 256, 0, stream>>>(Ahi, Alo, w1hi, w1lo, bufA, as1, ad1, esrc, edst, N, 256, DIN);
    gat_aggregate_hm_k<<<agg_grid, 256, 0, stream>>>(bufA, esrc, edst, rowptr, srcs, b1, Ahi, Alo, N);

    // Layer 2: 256 -> (4,64) concat
    gemm_lds_k<2><<<mb * 2, 256, 0, stream>>>(Ahi, Alo, w2hi, w2lo, bufA, as2, ad2, esrc, edst, N, 256, 256);
    gat_aggregate_hm_k<<<agg_grid, 256, 0, stream>>>(bufA, esrc, edst, rowptr, srcs, b2, Ahi, Alo, N);

    // Layer 3: 256 -> (1,64) mean + fused node-attention gate   (BN=64)
    gemm_lds_k<1><<<mb, 256, 0, stream>>>(Ahi, Alo, w3hi, w3lo, h3, as3, ad3, esrc, edst, N, 64, 256);
    gat_aggregate1_attn_k<<<nb4, 256, 0, stream>>>(h3, esrc, edst, rowptr, srcs, b3, wp, bp, g3, attn, N);

    // Attention pool + regressor (parallel)
    hipMemsetAsync(sums, 0, (size_t)Bc * 64 * 4, stream);
    pool_partial_k<<<256, 256, 0, stream>>>(g3, attn, bat, N, sums);
    regress_k<<<1, 1024, 0, stream>>>(sums, bat, N, wr, br, out, Bc);
}

// Round 11
// 277.044 us; speedup vs baseline: 1.0273x; 1.0053x over previous
//
#include <hip/hip_runtime.h>

// ---------------------------------------------------------------------------
// GAT (3 layers) + attention pooling + regressor.
// GEMMs: split-bf16 MFMA (a_hi+a_lo, 3 products, f32 accum), A staged in LDS
// via global_load_lds; attn scores fused into GEMM epilogue; h stored
// HEAD-MAJOR [H][N][64] (5.1MB/head gather set).
// Aggregates: {src,weight} pairs staged in LDS per 64-edge chunk -> inner loop
// is ds_read_b64 + lshl_add + dwordx4 + 4 fma per edge-quad (no shfl/clamps).
// N=20000 nodes, E=320000 edges (+N self loops), H=4 heads, C=64, B=16 graphs.
// ---------------------------------------------------------------------------

typedef unsigned short u16;
typedef __attribute__((ext_vector_type(8))) short bf16x8;
typedef __attribute__((ext_vector_type(4))) float f32x4;

__device__ __forceinline__ u16 bf16rn(float x) {
    unsigned u = __float_as_uint(x);
    u += 0x7FFFu + ((u >> 16) & 1u);
    return (u16)(u >> 16);
}
__device__ __forceinline__ float bf16f(u16 h) {
    return __uint_as_float(((unsigned)h) << 16);
}

__device__ __forceinline__ void gload16(const u16* g, u16* l) {
    __builtin_amdgcn_global_load_lds(
        (const __attribute__((address_space(1))) unsigned int*)g,
        (__attribute__((address_space(3))) unsigned int*)l, 16, 0, 0);
}

// ---------------- CSR-by-destination build ----------------
__global__ void edge_hist_k(const int* __restrict__ ei, int E, int n, int* __restrict__ deg) {
    int i = blockIdx.x * blockDim.x + threadIdx.x;
    if (i >= E + n) return;
    int dst = (i < E) ? ei[E + i] : (i - E);   // self-loop for i >= E
    atomicAdd(&deg[dst], 1);
}

__global__ __launch_bounds__(1024) void scan_excl_k(const int* __restrict__ deg, int* __restrict__ rowptr,
                                                    int* __restrict__ cursor, int n) {
    __shared__ int part[1024];
    int tid = threadIdx.x;
    int chunk = (n + 1023) / 1024;
    int lo = tid * chunk;
    int hi = lo + chunk;
    if (lo > n) lo = n;
    if (hi > n) hi = n;
    int s = 0;
    for (int i = lo; i < hi; ++i) s += deg[i];
    part[tid] = s;
    __syncthreads();
    for (int off = 1; off < 1024; off <<= 1) {
        int v = (tid >= off) ? part[tid - off] : 0;
        __syncthreads();
        part[tid] += v;
        __syncthreads();
    }
    int run = (tid == 0) ? 0 : part[tid - 1];
    for (int i = lo; i < hi; ++i) {
        rowptr[i] = run;
        cursor[i] = run;
        run += deg[i];
    }
    if (tid == 1023) rowptr[n] = run;
}

__global__ void edge_scatter_k(const int* __restrict__ ei, int E, int n,
                               int* __restrict__ cursor, int* __restrict__ srcs) {
    int i = blockIdx.x * blockDim.x + threadIdx.x;
    if (i >= E + n) return;
    int src, dst;
    if (i < E) { src = ei[i]; dst = ei[E + i]; }
    else       { src = i - E; dst = src; }
    int pos = atomicAdd(&cursor[dst], 1);
    srcs[pos] = src;
}

// ---------------- bf16 split conversions ----------------
__global__ void split_bf16_k(const float* __restrict__ in, u16* __restrict__ hi,
                             u16* __restrict__ lo, int n4) {
    int i = blockIdx.x * 256 + threadIdx.x;
    if (i >= n4) return;
    float4 v = reinterpret_cast<const float4*>(in)[i];
    u16 hx = bf16rn(v.x), hy = bf16rn(v.y), hz = bf16rn(v.z), hw = bf16rn(v.w);
    ushort4 H = make_ushort4(hx, hy, hz, hw);
    ushort4 L = make_ushort4(bf16rn(v.x - bf16f(hx)), bf16rn(v.y - bf16f(hy)),
                             bf16rn(v.z - bf16f(hz)), bf16rn(v.w - bf16f(hw)));
    reinterpret_cast<ushort4*>(hi)[i] = H;
    reinterpret_cast<ushort4*>(lo)[i] = L;
}

// W[K][Nn] row-major -> transposed split Wt[Nn][K] (hi, lo)
__global__ void splitT_bf16_k(const float* __restrict__ W, u16* __restrict__ thi,
                              u16* __restrict__ tlo, int K, int Nn) {
    int idx = blockIdx.x * 256 + threadIdx.x;
    if (idx >= K * Nn) return;
    int k = idx / Nn, nn = idx - k * Nn;
    float v = W[idx];
    u16 h = bf16rn(v);
    u16 l = bf16rn(v - bf16f(h));
    thi[(size_t)nn * K + k] = h;
    tlo[(size_t)nn * K + k] = l;
}

// ---------------- split-bf16 MFMA GEMM, LDS-staged A, fused attn scores ----
// C emitted HEAD-MAJOR: C[((col>>6)*M + row)*64 + (col&63)].
// Epilogue also emits esrc/edst [M][Nn/64]: per-row dot with a_src/a_dst.
template <int NF>
__global__ __launch_bounds__(256) void gemm_lds_k(
        const u16* __restrict__ Ahi, const u16* __restrict__ Alo,
        const u16* __restrict__ Bthi, const u16* __restrict__ Btlo,
        float* __restrict__ C,
        const float* __restrict__ a_src, const float* __restrict__ a_dst,
        float* __restrict__ esrc, float* __restrict__ edst,
        int M, int Nn, int K) {
    __shared__ u16 Ah[2][4][64 * 8];   // [buf][kg][row*8]
    __shared__ u16 Al[2][4][64 * 8];
    const int mb = (M + 63) >> 6;
    const int mi = blockIdx.x % mb;
    const int ni = blockIdx.x / mb;
    const int m0 = mi * 64;
    const int n0 = ni * (NF * 64);
    const int tid = threadIdx.x;
    const int wv = tid >> 6;
    const int lane = tid & 63;
    const int rr = lane & 15;
    const int kg = lane >> 4;

    int srow = m0 + lane; if (srow > M - 1) srow = M - 1;
    const u16* sh = Ahi + (size_t)srow * K + wv * 8;
    const u16* sl = Alo + (size_t)srow * K + wv * 8;

    const u16* pbh[NF];
    const u16* pbl[NF];
#pragma unroll
    for (int nf = 0; nf < NF; ++nf) {
        int col = n0 + (wv * NF + nf) * 16 + rr;
        pbh[nf] = Bthi + (size_t)col * K + kg * 8;
        pbl[nf] = Btlo + (size_t)col * K + kg * 8;
    }

    f32x4 acc[4][NF];
#pragma unroll
    for (int mf = 0; mf < 4; ++mf)
#pragma unroll
        for (int nf = 0; nf < NF; ++nf) acc[mf][nf] = (f32x4){0.f, 0.f, 0.f, 0.f};

    bf16x8 bhc[NF], blc[NF], bhn[NF], bln[NF];
#pragma unroll
    for (int nf = 0; nf < NF; ++nf) {
        bhc[nf] = *reinterpret_cast<const bf16x8*>(pbh[nf]);
        blc[nf] = *reinterpret_cast<const bf16x8*>(pbl[nf]);
    }
    gload16(sh, &Ah[0][wv][0]);
    gload16(sl, &Al[0][wv][0]);
    __syncthreads();

    const int NT = K >> 5;
    for (int t = 0; t < NT; ++t) {
        const int cur = t & 1;
        if (t + 1 < NT) {
            const int kc = (t + 1) << 5;
#pragma unroll
            for (int nf = 0; nf < NF; ++nf) {
                bhn[nf] = *reinterpret_cast<const bf16x8*>(pbh[nf] + kc);
                bln[nf] = *reinterpret_cast<const bf16x8*>(pbl[nf] + kc);
            }
            gload16(sh + kc, &Ah[cur ^ 1][wv][0]);
            gload16(sl + kc, &Al[cur ^ 1][wv][0]);
        }
        bf16x8 ah[4], al[4];
#pragma unroll
        for (int mf = 0; mf < 4; ++mf) {
            ah[mf] = *reinterpret_cast<const bf16x8*>(&Ah[cur][kg][(mf * 16 + rr) * 8]);
            al[mf] = *reinterpret_cast<const bf16x8*>(&Al[cur][kg][(mf * 16 + rr) * 8]);
        }
#pragma unroll
        for (int mf = 0; mf < 4; ++mf)
#pragma unroll
            for (int nf = 0; nf < NF; ++nf) {
                acc[mf][nf] = __builtin_amdgcn_mfma_f32_16x16x32_bf16(ah[mf], bhc[nf], acc[mf][nf], 0, 0, 0);
                acc[mf][nf] = __builtin_amdgcn_mfma_f32_16x16x32_bf16(ah[mf], blc[nf], acc[mf][nf], 0, 0, 0);
                acc[mf][nf] = __builtin_amdgcn_mfma_f32_16x16x32_bf16(al[mf], bhc[nf], acc[mf][nf], 0, 0, 0);
            }
#pragma unroll
        for (int nf = 0; nf < NF; ++nf) { bhc[nf] = bhn[nf]; blc[nf] = bln[nf]; }
        __syncthreads();
    }

    // ---- C store (head-major) ----
#pragma unroll
    for (int mf = 0; mf < 4; ++mf)
#pragma unroll
        for (int nf = 0; nf < NF; ++nf) {
            int col = n0 + (wv * NF + nf) * 16 + rr;
            float* cb = C + ((size_t)(col >> 6) * M) * 64 + (col & 63);
#pragma unroll
            for (int rg = 0; rg < 4; ++rg) {
                int row = m0 + mf * 16 + kg * 4 + rg;
                if (row < M) cb[(size_t)row * 64] = acc[mf][nf][rg];
            }
        }

    // ---- fused attention scores: per-row dot with a_src / a_dst ----
    float asv[NF], adv[NF];
#pragma unroll
    for (int nf = 0; nf < NF; ++nf) {
        int col = n0 + (wv * NF + nf) * 16 + rr;
        asv[nf] = a_src[col];
        adv[nf] = a_dst[col];
    }
    float ps[4][4], pd[4][4];   // [mf][rg]
#pragma unroll
    for (int mf = 0; mf < 4; ++mf)
#pragma unroll
        for (int rg = 0; rg < 4; ++rg) {
            float s = 0.f, dvv = 0.f;
#pragma unroll
            for (int nf = 0; nf < NF; ++nf) {
                s = fmaf(acc[mf][nf][rg], asv[nf], s);
                dvv = fmaf(acc[mf][nf][rg], adv[nf], dvv);
            }
#pragma unroll
            for (int off = 1; off < 16; off <<= 1) {
                s += __shfl_xor(s, off);
                dvv += __shfl_xor(dvv, off);
            }
            ps[mf][rg] = s;
            pd[mf][rg] = dvv;
        }
    // cross-wave combine via LDS (reuse Ah; all reads of it completed)
    float* sm_src = (float*)&Ah[0][0][0];     // [4 waves][64 rows]
    float* sm_dst = sm_src + 256;
    if (rr == 0) {
#pragma unroll
        for (int mf = 0; mf < 4; ++mf)
#pragma unroll
            for (int rg = 0; rg < 4; ++rg) {
                int rl = mf * 16 + kg * 4 + rg;
                sm_src[wv * 64 + rl] = ps[mf][rg];
                sm_dst[wv * 64 + rl] = pd[mf][rg];
            }
    }
    __syncthreads();
    if (tid < 64) {
        int row = m0 + tid;
        if (row < M) {
            const int HTOT = Nn >> 6;
            constexpr int WPH = 4 / NF;        // waves per head
#pragma unroll
            for (int hl = 0; hl < NF; ++hl) {
                float es = 0.f, edv = 0.f;
#pragma unroll
                for (int w = 0; w < WPH; ++w) {
                    es += sm_src[(hl * WPH + w) * 64 + tid];
                    edv += sm_dst[(hl * WPH + w) * 64 + tid];
                }
                int hg = ni * NF + hl;
                esrc[(size_t)row * HTOT + hg] = es;
                edst[(size_t)row * HTOT + hg] = edv;
            }
        }
    }
}

// ---------------- GAT aggregation, head-split, LDS-staged {src,w} pairs ----
// hm head-major [4][n][64]. Wave per (dst,head); lane = (es=lane>>4, cq=lane&15).
// Per 64-edge chunk: all lanes compute w, write {s,w} to LDS (padded lanes
// write w=0, valid s) -> inner loop is unguarded: ds_read_b64 + lshl_add +
// dwordx4 + 4 fma per edge-quad, 16 edges in flight.
__global__ __launch_bounds__(256) void gat_aggregate_hm_k(
        const float* __restrict__ hm, const float* __restrict__ esrc,
        const float* __restrict__ edst, const int* __restrict__ rowptr,
        const int* __restrict__ srcs, const float* __restrict__ bias,
        u16* __restrict__ ghi, u16* __restrict__ glo, int n) {
    __shared__ int2 swb[4][64];
    int wv = threadIdx.x >> 6;
    int d = blockIdx.x * 4 + wv;
    int lane = threadIdx.x & 63;
    int hh = blockIdx.y;                        // head
    if (d >= n) return;
    const float* hbase = hm + (size_t)hh * n * 64;
    const int es = lane >> 4;                   // edge sub-slot 0..3
    const int cq = lane & 15;                   // channel quad
    int2* swv = swb[wv];
    float ed = edst[d * 4 + hh];
    int lo = rowptr[d], hi = rowptr[d + 1];
    float4 acc = make_float4(0.f, 0.f, 0.f, 0.f);
    float den = 0.f;
    for (int base = lo; base < hi; base += 64) {
        int cnt = min(64, hi - base);
        int idx = base + lane;
        int s = srcs[(idx < hi) ? idx : lo];
        float e = esrc[s * 4 + hh] + ed;
        e = (e >= 0.f) ? e : 0.2f * e;          // leaky_relu(0.2)
        float w = (lane < cnt) ? __expf(e) : 0.f;
        float ws = w;
#pragma unroll
        for (int off = 1; off < 64; off <<= 1) ws += __shfl_xor(ws, off);
        den += ws;
        swv[lane] = make_int2(s, __float_as_int(w));   // same-wave LDS, no barrier
        auto ROW = [&](int2 sv) -> float4 {
            return *reinterpret_cast<const float4*>(&hbase[(size_t)sv.x * 64 + cq * 4]);
        };
        int2 s0 = swv[es], s1 = swv[4 + es], s2 = swv[8 + es], s3 = swv[12 + es];
        float4 p0 = ROW(s0), p1 = ROW(s1), p2 = ROW(s2), p3 = ROW(s3);
        for (int j = 0; j < cnt; j += 16) {
            int2 t0 = s0, t1 = s1, t2 = s2, t3 = s3;
            float4 q0 = p0, q1 = p1, q2 = p2, q3 = p3;
            s0 = swv[(j + 16 + es) & 63];
            s1 = swv[(j + 20 + es) & 63];
            s2 = swv[(j + 24 + es) & 63];
            s3 = swv[(j + 28 + es) & 63];
            p0 = ROW(s0); p1 = ROW(s1); p2 = ROW(s2); p3 = ROW(s3);
            float w0 = __int_as_float(t0.y), w1 = __int_as_float(t1.y);
            float w2 = __int_as_float(t2.y), w3 = __int_as_float(t3.y);
            acc.x = fmaf(w0, q0.x, acc.x); acc.y = fmaf(w0, q0.y, acc.y);
            acc.z = fmaf(w0, q0.z, acc.z); acc.w = fmaf(w0, q0.w, acc.w);
            acc.x = fmaf(w1, q1.x, acc.x); acc.y = fmaf(w1, q1.y, acc.y);
            acc.z = fmaf(w1, q1.z, acc.z); acc.w = fmaf(w1, q1.w, acc.w);
            acc.x = fmaf(w2, q2.x, acc.x); acc.y = fmaf(w2, q2.y, acc.y);
            acc.z = fmaf(w2, q2.z, acc.z); acc.w = fmaf(w2, q2.w, acc.w);
            acc.x = fmaf(w3, q3.x, acc.x); acc.y = fmaf(w3, q3.y, acc.y);
            acc.z = fmaf(w3, q3.z, acc.z); acc.w = fmaf(w3, q3.w, acc.w);
        }
    }
    // combine the 4 edge sub-slots (lanes differing in bits 4,5)
    acc.x += __shfl_xor(acc.x, 16); acc.x += __shfl_xor(acc.x, 32);
    acc.y += __shfl_xor(acc.y, 16); acc.y += __shfl_xor(acc.y, 32);
    acc.z += __shfl_xor(acc.z, 16); acc.z += __shfl_xor(acc.z, 32);
    acc.w += __shfl_xor(acc.w, 16); acc.w += __shfl_xor(acc.w, 32);
    if (es == 0) {
        int c0 = hh * 64 + cq * 4;
        float inv = 1.f / den;
        float4 bv = *reinterpret_cast<const float4*>(&bias[c0]);
        float4 o;
        o.x = acc.x * inv + bv.x;
        o.y = acc.y * inv + bv.y;
        o.z = acc.z * inv + bv.z;
        o.w = acc.w * inv + bv.w;
        o.x = (o.x > 0.f) ? o.x : expm1f(o.x);   // ELU
        o.y = (o.y > 0.f) ? o.y : expm1f(o.y);
        o.z = (o.z > 0.f) ? o.z : expm1f(o.z);
        o.w = (o.w > 0.f) ? o.w : expm1f(o.w);
        u16 hx = bf16rn(o.x), hy = bf16rn(o.y), hz = bf16rn(o.z), hw = bf16rn(o.w);
        ushort4 H = make_ushort4(hx, hy, hz, hw);
        ushort4 L = make_ushort4(bf16rn(o.x - bf16f(hx)), bf16rn(o.y - bf16f(hy)),
                                 bf16rn(o.z - bf16f(hz)), bf16rn(o.w - bf16f(hw)));
        *reinterpret_cast<ushort4*>(&ghi[(size_t)d * 256 + c0]) = H;
        *reinterpret_cast<ushort4*>(&glo[(size_t)d * 256 + c0]) = L;
    }
}

// ---------------- layer-3 aggregate (1 head) fused with node attn gate ------
// Same LDS {src,w} staging; full 64-ch dot for the gate.
__global__ __launch_bounds__(256) void gat_aggregate1_attn_k(
        const float* __restrict__ hin, const float* __restrict__ esrc,
        const float* __restrict__ edst, const int* __restrict__ rowptr,
        const int* __restrict__ srcs, const float* __restrict__ bias,
        const float* __restrict__ wp, const float* __restrict__ bp,
        float* __restrict__ gout, float* __restrict__ attn, int n) {
    __shared__ int2 swb[4][64];
    int wv = threadIdx.x >> 6;
    int d = blockIdx.x * 4 + wv;
    int lane = threadIdx.x & 63;
    if (d >= n) return;
    const int es = lane >> 4;
    const int cq = lane & 15;
    int2* swv = swb[wv];
    float ed = edst[d];
    int lo = rowptr[d], hi = rowptr[d + 1];
    float4 acc = make_float4(0.f, 0.f, 0.f, 0.f);
    float den = 0.f;
    for (int base = lo; base < hi; base += 64) {
        int cnt = min(64, hi - base);
        int idx = base + lane;
        int s = srcs[(idx < hi) ? idx : lo];
        float e = esrc[s] + ed;
        e = (e >= 0.f) ? e : 0.2f * e;
        float w = (lane < cnt) ? __expf(e) : 0.f;
        float ws = w;
#pragma unroll
        for (int off = 1; off < 64; off <<= 1) ws += __shfl_xor(ws, off);
        den += ws;
        swv[lane] = make_int2(s, __float_as_int(w));
        auto ROW = [&](int2 sv) -> float4 {
            return *reinterpret_cast<const float4*>(&hin[(size_t)sv.x * 64 + cq * 4]);
        };
        int2 s0 = swv[es], s1 = swv[4 + es], s2 = swv[8 + es], s3 = swv[12 + es];
        float4 p0 = ROW(s0), p1 = ROW(s1), p2 = ROW(s2), p3 = ROW(s3);
        for (int j = 0; j < cnt; j += 16) {
            int2 t0 = s0, t1 = s1, t2 = s2, t3 = s3;
            float4 q0 = p0, q1 = p1, q2 = p2, q3 = p3;
            s0 = swv[(j + 16 + es) & 63];
            s1 = swv[(j + 20 + es) & 63];
            s2 = swv[(j + 24 + es) & 63];
            s3 = swv[(j + 28 + es) & 63];
            p0 = ROW(s0); p1 = ROW(s1); p2 = ROW(s2); p3 = ROW(s3);
            float w0 = __int_as_float(t0.y), w1 = __int_as_float(t1.y);
            float w2 = __int_as_float(t2.y), w3 = __int_as_float(t3.y);
            acc.x = fmaf(w0, q0.x, acc.x); acc.y = fmaf(w0, q0.y, acc.y);
            acc.z = fmaf(w0, q0.z, acc.z); acc.w = fmaf(w0, q0.w, acc.w);
            acc.x = fmaf(w1, q1.x, acc.x); acc.y = fmaf(w1, q1.y, acc.y);
            acc.z = fmaf(w1, q1.z, acc.z); acc.w = fmaf(w1, q1.w, acc.w);
            acc.x = fmaf(w2, q2.x, acc.x); acc.y = fmaf(w2, q2.y, acc.y);
            acc.z = fmaf(w2, q2.z, acc.z); acc.w = fmaf(w2, q2.w, acc.w);
            acc.x = fmaf(w3, q3.x, acc.x); acc.y = fmaf(w3, q3.y, acc.y);
            acc.z = fmaf(w3, q3.z, acc.z); acc.w = fmaf(w3, q3.w, acc.w);
        }
    }
    acc.x += __shfl_xor(acc.x, 16); acc.x += __shfl_xor(acc.x, 32);
    acc.y += __shfl_xor(acc.y, 16); acc.y += __shfl_xor(acc.y, 32);
    acc.z += __shfl_xor(acc.z, 16); acc.z += __shfl_xor(acc.z, 32);
    acc.w += __shfl_xor(acc.w, 16); acc.w += __shfl_xor(acc.w, 32);
    int c0 = cq * 4;
    float inv = 1.f / den;
    float4 bv = *reinterpret_cast<const float4*>(&bias[c0]);
    float4 o;
    o.x = acc.x * inv + bv.x;
    o.y = acc.y * inv + bv.y;
    o.z = acc.z * inv + bv.z;
    o.w = acc.w * inv + bv.w;
    o.x = (o.x > 0.f) ? o.x : expm1f(o.x);       // ELU
    o.y = (o.y > 0.f) ? o.y : expm1f(o.y);
    o.z = (o.z > 0.f) ? o.z : expm1f(o.z);
    o.w = (o.w > 0.f) ? o.w : expm1f(o.w);
    if (es == 0)
        *reinterpret_cast<float4*>(&gout[(size_t)d * 64 + c0]) = o;
    // node attention gate: full 64-ch dot (cq lanes each hold 4 channels)
    float4 wv4 = *reinterpret_cast<const float4*>(&wp[c0]);
    float v = o.x * wv4.x + o.y * wv4.y + o.z * wv4.z + o.w * wv4.w;
#pragma unroll
    for (int off = 1; off < 16; off <<= 1) v += __shfl_xor(v, off);
    if (lane == 0) attn[d] = 1.f / (1.f + __expf(-(v + bp[0])));
}

// ---------------- parallel segmented pooling (batch is sorted) --------------
__global__ void pool_partial_k(const float* __restrict__ g3, const float* __restrict__ attn,
                               const int* __restrict__ batch, int n, float* __restrict__ sums) {
    int wid = blockIdx.x * (blockDim.x >> 6) + (threadIdx.x >> 6);
    int lane = threadIdx.x & 63;
    int nwaves = gridDim.x * (blockDim.x >> 6);
    int per = (n + nwaves - 1) / nwaves;
    int i0 = wid * per;
    int i1 = i0 + per;
    if (i1 > n) i1 = n;
    if (i0 >= i1) return;
    int cur = batch[i0];
    float acc = 0.f;
    for (int i = i0; i < i1; ++i) {
        int b = batch[i];
        if (b != cur) {
            atomicAdd(&sums[cur * 64 + lane], acc);
            acc = 0.f;
            cur = b;
        }
        acc += g3[(size_t)i * 64 + lane] * attn[i];
    }
    atomicAdd(&sums[cur * 64 + lane], acc);
}

// ---------------- final regressor: one block, wave per graph ----------------
__global__ void regress_k(const float* __restrict__ sums, const int* __restrict__ batch, int n,
                          const float* __restrict__ wr, const float* __restrict__ br,
                          float* __restrict__ out, int B) {
    int b = threadIdx.x >> 6;
    int lane = threadIdx.x & 63;
    if (b >= B) return;
    int lo = 0, hi = n;
    while (lo < hi) { int mid = (lo + hi) >> 1; if (batch[mid] < b) lo = mid + 1; else hi = mid; }
    int seg_lo = lo;
    lo = 0; hi = n;
    while (lo < hi) { int mid = (lo + hi) >> 1; if (batch[mid] < b + 1) lo = mid + 1; else hi = mid; }
    float cnt = (float)(lo - seg_lo);
    if (cnt < 1.f) cnt = 1.f;
    float v = (sums[b * 64 + lane] / cnt) * wr[lane];
#pragma unroll
    for (int off = 32; off; off >>= 1) v += __shfl_xor(v, off);
    if (lane == 0) out[b] = v + br[0];
}

// ---------------------------------------------------------------------------
extern "C" void kernel_launch(void* const* d_in, const int* in_sizes, int n_in,
                              void* d_out, int out_size, void* d_ws, size_t ws_size,
                              hipStream_t stream) {
    const float* x   = (const float*)d_in[0];
    const int*   ei  = (const int*)d_in[1];
    const int*   bat = (const int*)d_in[2];
    const float* W1  = (const float*)d_in[3];
    const float* as1 = (const float*)d_in[4];
    const float* ad1 = (const float*)d_in[5];
    const float* b1  = (const float*)d_in[6];
    const float* W2  = (const float*)d_in[7];
    const float* as2 = (const float*)d_in[8];
    const float* ad2 = (const float*)d_in[9];
    const float* b2  = (const float*)d_in[10];
    const float* W3  = (const float*)d_in[11];
    const float* as3 = (const float*)d_in[12];
    const float* ad3 = (const float*)d_in[13];
    const float* b3  = (const float*)d_in[14];
    const float* wp  = (const float*)d_in[15];
    const float* bp  = (const float*)d_in[16];
    const float* wr  = (const float*)d_in[17];
    const float* br  = (const float*)d_in[18];
    float* out = (float*)d_out;

    const int N    = in_sizes[2];          // 20000
    const int E    = in_sizes[1] / 2;      // 320000
    const int DIN  = in_sizes[0] / N;      // 128
    const int Etot = E + N;
    const int Bc   = out_size;             // 16

    char* ws = (char*)d_ws;
    size_t off = 0;
    auto alloc = [&](size_t bytes) {
        void* p = ws + off;
        off = (off + bytes + 255) & ~(size_t)255;
        return p;
    };
    int*   deg    = (int*)alloc((size_t)N * 4);
    int*   rowptr = (int*)alloc((size_t)(N + 1) * 4);
    int*   cursor = (int*)alloc((size_t)N * 4);
    int*   srcs   = (int*)alloc((size_t)Etot * 4);
    float* bufA   = (float*)alloc((size_t)N * 256 * 4);     // GEMM out h (head-major)
    u16*   Ahi    = (u16*)alloc((size_t)N * 256 * 2);       // x/g split hi
    u16*   Alo    = (u16*)alloc((size_t)N * 256 * 2);       // x/g split lo
    float* h3     = (float*)alloc((size_t)N * 64 * 4);
    float* g3     = (float*)alloc((size_t)N * 64 * 4);
    float* esrc   = (float*)alloc((size_t)N * 4 * 4);
    float* edst   = (float*)alloc((size_t)N * 4 * 4);
    float* attn   = (float*)alloc((size_t)N * 4);
    float* sums   = (float*)alloc((size_t)Bc * 64 * 4);
    u16*   w1hi   = (u16*)alloc((size_t)256 * DIN * 2);
    u16*   w1lo   = (u16*)alloc((size_t)256 * DIN * 2);
    u16*   w2hi   = (u16*)alloc((size_t)256 * 256 * 2);
    u16*   w2lo   = (u16*)alloc((size_t)256 * 256 * 2);
    u16*   w3hi   = (u16*)alloc((size_t)64 * 256 * 2);
    u16*   w3lo   = (u16*)alloc((size_t)64 * 256 * 2);
    (void)ws_size;

    // CSR build (shared by all layers)
    hipMemsetAsync(deg, 0, (size_t)N * 4, stream);
    int eb = (Etot + 255) / 256;
    edge_hist_k<<<eb, 256, 0, stream>>>(ei, E, N, deg);
    scan_excl_k<<<1, 1024, 0, stream>>>(deg, rowptr, cursor, N);
    edge_scatter_k<<<eb, 256, 0, stream>>>(ei, E, N, cursor, srcs);

    // weight splits (transposed) + x split
    splitT_bf16_k<<<(DIN * 256 + 255) / 256, 256, 0, stream>>>(W1, w1hi, w1lo, DIN, 256);
    splitT_bf16_k<<<(256 * 256 + 255) / 256, 256, 0, stream>>>(W2, w2hi, w2lo, 256, 256);
    splitT_bf16_k<<<(256 * 64 + 255) / 256, 256, 0, stream>>>(W3, w3hi, w3lo, 256, 64);
    split_bf16_k<<<(N * DIN / 4 + 255) / 256, 256, 0, stream>>>(x, Ahi, Alo, N * DIN / 4);

    const int mb = (N + 63) / 64;          // 313
    int nb4 = (N + 3) / 4;
    dim3 agg_grid(nb4, 4);

    // Layer 1: DIN -> (4,64) concat      (BN=128 -> 2 n-tiles)
    gemm_lds_k<2><<<mb * 2, 256, 0, stream>>>(Ahi, Alo, w1hi, w1lo, bufA, as1, ad1, esrc, edst, N, 256, DIN);
    gat_aggregate_hm_k<<<agg_grid, 256, 0, stream>>>(bufA, esrc, edst, rowptr, srcs, b1, Ahi, Alo, N);

    // Layer 2: 256 -> (4,64) concat
    gemm_lds_k<2><<<mb * 2, 256, 0, stream>>>(Ahi, Alo, w2hi, w2lo, bufA, as2, ad2, esrc, edst, N, 256, 256);
    gat_aggregate_hm_k<<<agg_grid, 256, 0, stream>>>(bufA, esrc, edst, rowptr, srcs, b2, Ahi, Alo, N);

    // Layer 3: 256 -> (1,64) mean + fused node-attention gate   (BN=64)
    gemm_lds_k<1><<<mb, 256, 0, stream>>>(Ahi, Alo, w3hi, w3lo, h3, as3, ad3, esrc, edst, N, 64, 256);
    gat_aggregate1_attn_k<<<nb4, 256, 0, stream>>>(h3, esrc, edst, rowptr, srcs, b3, wp, bp, g3, attn, N);

    // Attention pool + regressor (parallel)
    hipMemsetAsync(sums, 0, (size_t)Bc * 64 * 4, stream);
    pool_partial_k<<<256, 256, 0, stream>>>(g3, attn, bat, N, sums);
    regress_k<<<1, 1024, 0, stream>>>(sums, bat, N, wr, br, out, Bc);
}